// Round 2
// baseline (13408.539 us; speedup 1.0000x reference)
//
#include <hip/hip_runtime.h>

// Residual VQ forward: x [B=16, D=256, T=4096] fp32, codebooks [NQ=8, BINS=1024, D=256] fp32.
// d_out = quantized [B,D,T] fp32 (16,777,216) ++ codes [NQ,B,T] as float (524,288).
// Identity: quantized = x - residual_final.
// Correctness strategy: fp32 scoring pass tracks top-2 per token; if margin <= DELTA,
// re-score the two candidates in fp64 (exact argmax w.h.p.).

#define BB   16
#define DD   256
#define TT   4096
#define NQ   8
#define BINS 1024

#define TOK_PER_BLK 32
#define BIN_CHUNK   128
#define KC          32     // d-slice per staging step
#define EPAD        36     // e_lds row stride (floats)
#define RPAD        260    // r_lds row stride (floats)
#define DELTA       0.0078125f   // 2^-7: >> fp32 score error (~1e-5), << typical top-2 gap (~8)

// lexicographic top-2 update: (score desc, index asc)
#define UPD2(S, BIN, B1, I1, B2, I2)                                        \
    if ((S) > (B2) || ((S) == (B2) && (BIN) < (I2))) {                      \
        if ((S) > (B1) || ((S) == (B1) && (BIN) < (I1))) {                  \
            B2 = B1; I2 = I1; B1 = (S); I1 = (BIN);                         \
        } else { B2 = (S); I2 = (BIN); }                                    \
    }

__global__ __launch_bounds__(256, 2)
void rvq_esq_kernel(const float* __restrict__ cb, float* __restrict__ esq) {
    int q = blockIdx.x;
    const float* e = cb + (size_t)q * BINS * DD;
    for (int bin = threadIdx.x; bin < BINS; bin += 256) {
        const float4* row = (const float4*)(e + (size_t)bin * DD);
        float s = 0.f;
        #pragma unroll 8
        for (int i = 0; i < DD / 4; ++i) {
            float4 v = row[i];
            s += v.x * v.x + v.y * v.y + v.z * v.z + v.w * v.w;
        }
        esq[q * BINS + bin] = s;
    }
}

__global__ __launch_bounds__(256, 2)
void rvq_main_kernel(const float* __restrict__ x, const float* __restrict__ cb,
                     const float* __restrict__ esq, float* __restrict__ out) {
    __shared__ float r_lds[TOK_PER_BLK][RPAD];
    __shared__ float e_lds[BIN_CHUNK][EPAD];
    __shared__ float red_s[16][2][TOK_PER_BLK];
    __shared__ int   red_i[16][2][TOK_PER_BLK];
    __shared__ int   best_lds[TOK_PER_BLK];

    const int tid = threadIdx.x;
    const int blk = blockIdx.x;
    const int b   = blk >> 7;                 // 128 blocks per batch element
    const int t0  = (blk & 127) * TOK_PER_BLK;

    // ---- init: r_lds[t][d] = x[b, d, t0+t]  (coalesced over t) ----
    {
        const int tl = tid & 31;
        const int d0 = (tid >> 5) * 32;
        const float* xp = x + (size_t)b * DD * TT + t0 + tl;
        for (int dd = 0; dd < 32; ++dd) {
            int d = d0 + dd;
            r_lds[tl][d] = xp[(size_t)d * TT];
        }
    }
    __syncthreads();

    const int ty = tid >> 4;   // 0..15  -> bin group
    const int tx = tid & 15;   // 0..15  -> token (and token+16)

    for (int q = 0; q < NQ; ++q) {
        const float* eb = cb + (size_t)q * BINS * DD;
        const float* es = esq + q * BINS;
        // per-thread top-2 for token tx (slot 0) and token tx+16 (slot 1)
        float b1[2] = {-1e30f, -1e30f}, b2[2] = {-1e30f, -1e30f};
        int   i1[2] = {0x7fffffff, 0x7fffffff}, i2[2] = {0x7fffffff, 0x7fffffff};

        for (int c = 0; c < BINS / BIN_CHUNK; ++c) {        // 8 chunks of 128 bins
            float acc[2][8];
            #pragma unroll
            for (int i = 0; i < 2; ++i)
                #pragma unroll
                for (int j = 0; j < 8; ++j) acc[i][j] = 0.f;

            for (int kc = 0; kc < DD / KC; ++kc) {          // 8 k-slices of 32
                __syncthreads();
                // stage codebook tile [128 bins][32 d] -> e_lds
                {
                    const int col  = tid & 7;               // float4 column (0..7)
                    const int row0 = tid >> 3;              // 0..31
                    const float* src = eb + (size_t)(c * BIN_CHUNK) * DD + kc * KC;
                    #pragma unroll
                    for (int rr = 0; rr < 4; ++rr) {
                        int row = row0 + rr * 32;
                        float4 v = *(const float4*)(src + (size_t)row * DD + col * 4);
                        *(float4*)&e_lds[row][col * 4] = v;
                    }
                }
                __syncthreads();
                // accumulate dots
                #pragma unroll
                for (int k4 = 0; k4 < KC / 4; ++k4) {
                    float4 r0 = *(const float4*)&r_lds[tx][kc * KC + k4 * 4];
                    float4 r1 = *(const float4*)&r_lds[tx + 16][kc * KC + k4 * 4];
                    #pragma unroll
                    for (int bi = 0; bi < 8; ++bi) {
                        float4 e4 = *(const float4*)&e_lds[ty + 16 * bi][k4 * 4];
                        acc[0][bi] += r0.x * e4.x + r0.y * e4.y + r0.z * e4.z + r0.w * e4.w;
                        acc[1][bi] += r1.x * e4.x + r1.y * e4.y + r1.z * e4.z + r1.w * e4.w;
                    }
                }
            }
            // fold -0.5*e_sq, update per-thread top-2
            #pragma unroll
            for (int bi = 0; bi < 8; ++bi) {
                int bin = c * BIN_CHUNK + ty + 16 * bi;
                float half_esq = 0.5f * es[bin];
                float s0 = acc[0][bi] - half_esq;
                float s1 = acc[1][bi] - half_esq;
                UPD2(s0, bin, b1[0], i1[0], b2[0], i2[0]);
                UPD2(s1, bin, b1[1], i1[1], b2[1], i2[1]);
            }
        }

        // write per-thread top-2 to LDS
        #pragma unroll
        for (int k = 0; k < 2; ++k) {
            red_s[ty][k][tx]      = k ? b2[0] : b1[0];
            red_i[ty][k][tx]      = k ? i2[0] : i1[0];
            red_s[ty][k][tx + 16] = k ? b2[1] : b1[1];
            red_i[ty][k][tx + 16] = k ? i2[1] : i1[1];
        }
        __syncthreads();

        if (tid < TOK_PER_BLK) {
            // merge 32 candidates -> global top-2
            float g1 = -1e30f, g2 = -1e30f; int gi1 = 0x7fffffff, gi2 = 0x7fffffff;
            #pragma unroll
            for (int j = 0; j < 16; ++j) {
                #pragma unroll
                for (int k = 0; k < 2; ++k) {
                    float s = red_s[j][k][tid]; int ii = red_i[j][k][tid];
                    UPD2(s, ii, g1, gi1, g2, gi2);
                }
            }
            int bif;
            if (g1 - g2 <= DELTA) {
                // near-tie: exact fp64 re-score of the two candidates
                const float* rrow = r_lds[tid];
                double sc[2]; int id2[2] = { gi1, gi2 };
                for (int cc = 0; cc < 2; ++cc) {
                    const float* ep = eb + (size_t)id2[cc] * DD;
                    double acc = 0.0;
                    #pragma unroll 4
                    for (int d = 0; d < DD; ++d) {
                        double ev = (double)ep[d];
                        acc += ev * (2.0 * (double)rrow[d] - ev);   // 2 r·e - e^2
                    }
                    sc[cc] = acc;
                }
                // compare 0.5*true-score; same order as reference argmax (first index on tie)
                bif = (sc[0] > sc[1] || (sc[0] == sc[1] && id2[0] < id2[1])) ? id2[0] : id2[1];
            } else {
                bif = gi1;
            }
            best_lds[tid] = bif;
            out[(size_t)BB * DD * TT + (size_t)q * (BB * TT) + (size_t)b * TT + t0 + tid]
                = (float)bif;
        }
        __syncthreads();

        // residual update: r[tok][:] -= codebook[best][:]
        {
            const int tok  = tid >> 3;
            const int part = tid & 7;
            const int bin  = best_lds[tok];
            const float* ep = eb + (size_t)bin * DD + part * 32;
            float* rp = &r_lds[tok][part * 32];
            #pragma unroll
            for (int dd = 0; dd < 32; ++dd) rp[dd] -= ep[dd];
        }
        __syncthreads();
    }

    // ---- final: quantized[b,d,t] = x[b,d,t] - r_final ----
    {
        const int tl = tid & 31;
        const int d0 = (tid >> 5) * 32;
        const float* xp = x + (size_t)b * DD * TT + t0 + tl;
        float*       op = out + (size_t)b * DD * TT + t0 + tl;
        for (int dd = 0; dd < 32; ++dd) {
            int d = d0 + dd;
            op[(size_t)d * TT] = xp[(size_t)d * TT] - r_lds[tl][d];
        }
    }
}

extern "C" void kernel_launch(void* const* d_in, const int* in_sizes, int n_in,
                              void* d_out, int out_size, void* d_ws, size_t ws_size,
                              hipStream_t stream) {
    const float* x  = (const float*)d_in[0];
    const float* cb = (const float*)d_in[1];
    float* out = (float*)d_out;
    float* esq = (float*)d_ws;   // NQ*BINS floats = 32 KB scratch

    rvq_esq_kernel<<<NQ, 256, 0, stream>>>(cb, esq);
    rvq_main_kernel<<<(BB * TT) / TOK_PER_BLK, 256, 0, stream>>>(x, cb, esq, out);
}

// Round 3
// 841.279 us; speedup vs baseline: 15.9383x; 15.9383x over previous
//
#include <hip/hip_runtime.h>

// Residual VQ forward: x [B=16, D=256, T=4096] fp32, codebooks [NQ=8, BINS=1024, D=256] fp32.
// d_out = quantized [B,D,T] fp32 ++ codes [NQ,B,T] as float.
// MFMA path: split-bf16 (hi/lo) 3-term GEMM for scores, top-2 + fp64-exact refinement gate.

#define BB   16
#define DD   256
#define TT   4096
#define NQ   8
#define BINS 1024
#define DELTA 0.0078125f
#define OUTQ ((size_t)BB * DD * TT)

typedef __attribute__((ext_vector_type(8))) short bfrag;
typedef __attribute__((ext_vector_type(4))) float facc;

__device__ inline float bfh2f(unsigned short h) {
    union { unsigned u; float f; } c; c.u = ((unsigned)h) << 16; return c.f;
}
__device__ inline unsigned short f2bf(float f) {
    union { float f; unsigned u; } c; c.f = f;
    unsigned r = c.u + 0x7fff + ((c.u >> 16) & 1);
    return (unsigned short)(r >> 16);
}

#define MFMA(A, B, C) __builtin_amdgcn_mfma_f32_16x16x32_bf16((A), (B), (C), 0, 0, 0)

#define UPD2(S, BIN, S1, I1, S2, I2) { \
    bool _g1 = (S) > (S1); \
    bool _g2 = (S) > (S2); \
    S2 = _g1 ? (S1) : (_g2 ? (S) : (S2)); \
    I2 = _g1 ? (I1) : (_g2 ? (BIN) : (I2)); \
    S1 = _g1 ? (S) : (S1); \
    I1 = _g1 ? (BIN) : (I1); }

// ---------- pack kernel: fp32 codebook -> (hi<<16)|lo bf16 pairs ----------
__global__ __launch_bounds__(256)
void rvq_pack(const float* __restrict__ cb, unsigned* __restrict__ pk) {
    int i = blockIdx.x * 256 + threadIdx.x;           // float4 index
    float4 v = ((const float4*)cb)[i];
    float vv[4] = { v.x, v.y, v.z, v.w };
    uint4 o;
    unsigned oo[4];
    #pragma unroll
    for (int k = 0; k < 4; ++k) {
        unsigned short h = f2bf(vv[k]);
        float rem = vv[k] - bfh2f(h);
        unsigned short lo = f2bf(rem);
        oo[k] = (((unsigned)h) << 16) | lo;
    }
    o.x = oo[0]; o.y = oo[1]; o.z = oo[2]; o.w = oo[3];
    ((uint4*)pk)[i] = o;
}

__global__ __launch_bounds__(256)
void rvq_esq_half(const float* __restrict__ cb, float* __restrict__ hesq) {
    int q = blockIdx.x;
    const float* e = cb + (size_t)q * BINS * DD;
    for (int bin = threadIdx.x; bin < BINS; bin += 256) {
        const float4* row = (const float4*)(e + (size_t)bin * DD);
        float s = 0.f;
        #pragma unroll 8
        for (int i = 0; i < DD / 4; ++i) {
            float4 v = row[i];
            s += v.x * v.x + v.y * v.y + v.z * v.z + v.w * v.w;
        }
        hesq[q * BINS + bin] = 0.5f * s;
    }
}

// ---------- main MFMA kernel ----------
__global__ __launch_bounds__(512, 2)
void rvq_mfma_kernel(const float* __restrict__ x, const float* __restrict__ cb,
                     const unsigned* __restrict__ pk, const float* __restrict__ hesq,
                     float* __restrict__ out)
{
    // btile[buf][hi/lo][plane = nf*8+s][512 shorts]: each plane = one 16x32 B-fragment,
    // stored in exact wave-read order (lane-linear 1KB) -> conflict-free ds_read_b128.
    __shared__ alignas(16) short btile[2][2][16][512];
    __shared__ unsigned short best_lds[8][32];
    __shared__ unsigned short hist_lds[8][NQ][32];

    const int tid = threadIdx.x;
    const int w   = tid >> 6;
    const int l   = tid & 63;
    const int c   = l & 15;
    const int g   = l >> 4;

    const int blk = blockIdx.x;        // 256 blocks
    const int b   = blk >> 4;
    const int t0  = (blk & 15) * 256;
    const int tw  = t0 + w * 32;

    // staging thread mapping
    const int sc   = tid & 15;
    const int skq  = (tid >> 4) & 15;
    const int snf  = tid >> 8;
    const int splane = snf * 8 + (skq >> 1);
    const int sg0    = (skq & 1) * 2;

    auto paddr = [&](int ccn) -> const uint4* {
        ccn &= 255;
        int qq = ccn >> 5, chh = ccn & 31;
        return (const uint4*)(pk + (size_t)((qq * BINS + chh * 32 + snf * 16 + sc) * DD) + skq * 16);
    };

    uint4 rA0, rA1, rA2, rA3, rB0, rB1, rB2, rB3;
#define LOAD4(P, SRC) do { const uint4* _s4 = (SRC); P##0 = _s4[0]; P##1 = _s4[1]; P##2 = _s4[2]; P##3 = _s4[3]; } while (0)

#define STAGE_WRITE(R0, R1, R2, R3, BU) do { \
    unsigned _u[16] = { R0.x, R0.y, R0.z, R0.w, R1.x, R1.y, R1.z, R1.w, \
                        R2.x, R2.y, R2.z, R2.w, R3.x, R3.y, R3.z, R3.w }; \
    bfrag _h0, _h1, _l0, _l1; \
    _Pragma("unroll") \
    for (int _e = 0; _e < 8; ++_e) { \
        _h0[_e] = (short)(_u[_e] >> 16);     _l0[_e] = (short)(_u[_e] & 0xffffu); \
        _h1[_e] = (short)(_u[8 + _e] >> 16); _l1[_e] = (short)(_u[8 + _e] & 0xffffu); \
    } \
    *(bfrag*)&btile[BU][0][splane][sg0 * 128 + sc * 8]       = _h0; \
    *(bfrag*)&btile[BU][0][splane][(sg0 + 1) * 128 + sc * 8] = _h1; \
    *(bfrag*)&btile[BU][1][splane][sg0 * 128 + sc * 8]       = _l0; \
    *(bfrag*)&btile[BU][1][splane][(sg0 + 1) * 128 + sc * 8] = _l1; \
} while (0)

    // issue first two chunk loads early
    LOAD4(rA, paddr(0));
    LOAD4(rB, paddr(1));

    // ---- A init: residual = x, split to hi/lo MFMA fragments ----
    bfrag ah[2][8], al[2][8];
    {
        const float* xb = x + (size_t)b * DD * TT;
        #pragma unroll
        for (int m = 0; m < 2; ++m) {
            int t = tw + m * 16 + c;
            #pragma unroll
            for (int s = 0; s < 8; ++s) {
                #pragma unroll
                for (int j = 0; j < 8; ++j) {
                    int d = s * 32 + g * 8 + j;
                    float v = xb[(size_t)d * TT + t];
                    unsigned short h = f2bf(v);
                    float rem = v - bfh2f(h);
                    ah[m][s][j] = (short)h;
                    al[m][s][j] = (short)f2bf(rem);
                }
            }
        }
    }

    STAGE_WRITE(rA0, rA1, rA2, rA3, 0);
    __syncthreads();

    // per-slot top-2 state: slot (m, j) = token m*16 + 4*g + j
    float s1[2][4], s2[2][4];
    int   i1[2][4], i2[2][4];

    auto reset_slots = [&]() {
        #pragma unroll
        for (int m = 0; m < 2; ++m)
            #pragma unroll
            for (int j = 0; j < 4; ++j) {
                s1[m][j] = -1e30f; s2[m][j] = -1e30f;
                i1[m][j] = 0x7fffffff; i2[m][j] = 0x7fffffff;
            }
    };

    auto compute_chunk = [&](int bu, int qq, int ch) {
        facc a00 = {0.f,0.f,0.f,0.f}, a01 = {0.f,0.f,0.f,0.f};
        facc a10 = {0.f,0.f,0.f,0.f}, a11 = {0.f,0.f,0.f,0.f};
        const int roff = g * 128 + c * 8;
        __builtin_amdgcn_s_setprio(1);
        #pragma unroll
        for (int s = 0; s < 8; ++s) {
            bfrag bh0 = *(const bfrag*)&btile[bu][0][s][roff];
            bfrag bh1 = *(const bfrag*)&btile[bu][0][8 + s][roff];
            bfrag bl0 = *(const bfrag*)&btile[bu][1][s][roff];
            bfrag bl1 = *(const bfrag*)&btile[bu][1][8 + s][roff];
            a00 = MFMA(ah[0][s], bh0, a00);
            a10 = MFMA(ah[1][s], bh0, a10);
            a01 = MFMA(ah[0][s], bh1, a01);
            a11 = MFMA(ah[1][s], bh1, a11);
            a00 = MFMA(al[0][s], bh0, a00);
            a10 = MFMA(al[1][s], bh0, a10);
            a01 = MFMA(al[0][s], bh1, a01);
            a11 = MFMA(al[1][s], bh1, a11);
            a00 = MFMA(ah[0][s], bl0, a00);
            a10 = MFMA(ah[1][s], bl0, a10);
            a01 = MFMA(ah[0][s], bl1, a01);
            a11 = MFMA(ah[1][s], bl1, a11);
        }
        __builtin_amdgcn_s_setprio(0);
        const float* hq = hesq + qq * BINS + ch * 32;
        float q0 = hq[c], q1 = hq[16 + c];
        int bin0 = ch * 32 + c;
        #pragma unroll
        for (int j = 0; j < 4; ++j) {
            float v;
            v = a00[j] - q0; UPD2(v, bin0,      s1[0][j], i1[0][j], s2[0][j], i2[0][j]);
            v = a01[j] - q1; UPD2(v, bin0 + 16, s1[0][j], i1[0][j], s2[0][j], i2[0][j]);
            v = a10[j] - q0; UPD2(v, bin0,      s1[1][j], i1[1][j], s2[1][j], i2[1][j]);
            v = a11[j] - q1; UPD2(v, bin0 + 16, s1[1][j], i1[1][j], s2[1][j], i2[1][j]);
        }
    };

    auto stage_end = [&](int qq) {
        // cross-lane top-2 merge over the 16 column lanes
        #pragma unroll
        for (int m = 0; m < 2; ++m)
            #pragma unroll
            for (int j = 0; j < 4; ++j) {
                float a1 = s1[m][j], a2 = s2[m][j];
                int   x1 = i1[m][j], x2 = i2[m][j];
                #pragma unroll
                for (int mk = 1; mk < 16; mk <<= 1) {
                    float b1 = __shfl_xor(a1, mk), b2 = __shfl_xor(a2, mk);
                    int   y1 = __shfl_xor(x1, mk), y2 = __shfl_xor(x2, mk);
                    bool bG = (b1 > a1) || (b1 == a1 && y1 < x1);
                    float w1 = bG ? b1 : a1; int wi1 = bG ? y1 : x1;
                    float ls = bG ? a1 : b1; int li  = bG ? x1 : y1;
                    float o2 = bG ? b2 : a2; int oi  = bG ? y2 : x2;
                    bool sG = (ls > o2) || (ls == o2 && li < oi);
                    a1 = w1; x1 = wi1;
                    a2 = sG ? ls : o2; x2 = sG ? li : oi;
                }
                s1[m][j] = a1; i1[m][j] = x1; s2[m][j] = a2; i2[m][j] = x2;
            }

        int bch[2][4];
        bool need = false;
        #pragma unroll
        for (int m = 0; m < 2; ++m)
            #pragma unroll
            for (int j = 0; j < 4; ++j) {
                bch[m][j] = i1[m][j];
                need = need || (s1[m][j] - s2[m][j] <= DELTA);
            }

        if (__any(need)) {
            // rare: exact fp32 residual chain + fp64 re-score of the two candidates
            #pragma unroll
            for (int m = 0; m < 2; ++m)
                #pragma unroll
                for (int j = 0; j < 4; ++j) {
                    unsigned long long nm = __ballot(s1[m][j] - s2[m][j] <= DELTA);
                    if (nm) {
                        for (int g2 = 0; g2 < 4; ++g2) {
                            if ((nm >> (g2 * 16)) & 1ull) {
                                int c1 = __shfl(i1[m][j], g2 * 16);
                                int c2 = __shfl(i2[m][j], g2 * 16);
                                int tkl = m * 16 + g2 * 4 + j;
                                int t = tw + tkl;
                                double p1 = 0.0, p2 = 0.0;
                                const float* e1p = cb + (size_t)(qq * BINS + c1) * DD;
                                const float* e2p = cb + (size_t)(qq * BINS + c2) * DD;
                                #pragma unroll
                                for (int dd = 0; dd < 4; ++dd) {
                                    int d = l * 4 + dd;
                                    float rv = x[((size_t)b * DD + d) * TT + t];
                                    for (int k = 0; k < qq; ++k) {
                                        int hb = hist_lds[w][k][tkl];
                                        rv -= cb[(size_t)(k * BINS + hb) * DD + d];
                                    }
                                    float e1v = e1p[d], e2v = e2p[d];
                                    p1 += (double)e1v * (2.0 * (double)rv - (double)e1v);
                                    p2 += (double)e2v * (2.0 * (double)rv - (double)e2v);
                                }
                                #pragma unroll
                                for (int mk = 1; mk < 64; mk <<= 1) {
                                    p1 += __shfl_xor(p1, mk);
                                    p2 += __shfl_xor(p2, mk);
                                }
                                int wb = (p1 > p2 || (p1 == p2 && c1 < c2)) ? c1 : c2;
                                if (g == g2) bch[m][j] = wb;
                            }
                        }
                    }
                }
        }

        // writes: codes + per-wave best/history
        if (c == 0) {
            #pragma unroll
            for (int m = 0; m < 2; ++m)
                #pragma unroll
                for (int j = 0; j < 4; ++j) {
                    int tkl = m * 16 + g * 4 + j;
                    best_lds[w][tkl] = (unsigned short)bch[m][j];
                    hist_lds[w][qq][tkl] = (unsigned short)bch[m][j];
                    out[OUTQ + ((size_t)qq * BB + b) * TT + tw + tkl] = (float)bch[m][j];
                }
        }

        // residual update: r -= e[best], re-split to hi/lo
        #pragma unroll
        for (int m = 0; m < 2; ++m) {
            int bin = best_lds[w][m * 16 + c];
            const unsigned* ep = pk + (size_t)(qq * BINS + bin) * DD + g * 8;
            #pragma unroll
            for (int s = 0; s < 8; ++s) {
                uint4 u0 = *(const uint4*)(ep + s * 32);
                uint4 u1 = *(const uint4*)(ep + s * 32 + 4);
                unsigned uu[8] = { u0.x, u0.y, u0.z, u0.w, u1.x, u1.y, u1.z, u1.w };
                #pragma unroll
                for (int j = 0; j < 8; ++j) {
                    float rv = bfh2f((unsigned short)ah[m][s][j]) + bfh2f((unsigned short)al[m][s][j]);
                    float ev = bfh2f((unsigned short)(uu[j] >> 16)) + bfh2f((unsigned short)(uu[j] & 0xffffu));
                    float nr = rv - ev;
                    unsigned short nh = f2bf(nr);
                    float rem = nr - bfh2f(nh);
                    ah[m][s][j] = (short)nh;
                    al[m][s][j] = (short)f2bf(rem);
                }
            }
        }
    };

    // ---- main loop: 8 stages x 32 chunks, 1 barrier per chunk ----
    for (int q = 0; q < NQ; ++q) {
        reset_slots();
        for (int ch = 0; ch < 32; ch += 2) {
            int cc = q * 32 + ch;
            LOAD4(rA, paddr(cc + 2));
            STAGE_WRITE(rB0, rB1, rB2, rB3, 1);
            compute_chunk(0, q, ch);
            __syncthreads();
            LOAD4(rB, paddr(cc + 3));
            STAGE_WRITE(rA0, rA1, rA2, rA3, 0);
            compute_chunk(1, q, ch + 1);
            if (ch == 30) stage_end(q);
            __syncthreads();
        }
    }

    // ---- final: quantized = x - residual ----
    {
        const float* xb = x + (size_t)b * DD * TT;
        float* ob = out + (size_t)b * DD * TT;
        #pragma unroll
        for (int m = 0; m < 2; ++m) {
            int t = tw + m * 16 + c;
            #pragma unroll
            for (int s = 0; s < 8; ++s)
                #pragma unroll
                for (int j = 0; j < 8; ++j) {
                    int d = s * 32 + g * 8 + j;
                    float rv = bfh2f((unsigned short)ah[m][s][j]) + bfh2f((unsigned short)al[m][s][j]);
                    ob[(size_t)d * TT + t] = xb[(size_t)d * TT + t] - rv;
                }
        }
    }
}

// ================= fallback fp32 path (round-2, known-good) =================
#define TOK_PER_BLK 32
#define BIN_CHUNK   128
#define KC          32
#define EPAD        36
#define RPAD        260

#define FUPD2(S, BIN, B1, I1, B2, I2)                                        \
    if ((S) > (B2) || ((S) == (B2) && (BIN) < (I2))) {                      \
        if ((S) > (B1) || ((S) == (B1) && (BIN) < (I1))) {                  \
            B2 = B1; I2 = I1; B1 = (S); I1 = (BIN);                         \
        } else { B2 = (S); I2 = (BIN); }                                    \
    }

__global__ __launch_bounds__(256, 2)
void rvq_esq_kernel(const float* __restrict__ cb, float* __restrict__ esq) {
    int q = blockIdx.x;
    const float* e = cb + (size_t)q * BINS * DD;
    for (int bin = threadIdx.x; bin < BINS; bin += 256) {
        const float4* row = (const float4*)(e + (size_t)bin * DD);
        float s = 0.f;
        #pragma unroll 8
        for (int i = 0; i < DD / 4; ++i) {
            float4 v = row[i];
            s += v.x * v.x + v.y * v.y + v.z * v.z + v.w * v.w;
        }
        esq[q * BINS + bin] = s;
    }
}

__global__ __launch_bounds__(256, 2)
void rvq_main_kernel(const float* __restrict__ x, const float* __restrict__ cb,
                     const float* __restrict__ esq, float* __restrict__ out) {
    __shared__ float r_lds[TOK_PER_BLK][RPAD];
    __shared__ float e_lds[BIN_CHUNK][EPAD];
    __shared__ float red_s[16][2][TOK_PER_BLK];
    __shared__ int   red_i[16][2][TOK_PER_BLK];
    __shared__ int   best_lds[TOK_PER_BLK];

    const int tid = threadIdx.x;
    const int blk = blockIdx.x;
    const int b   = blk >> 7;
    const int t0  = (blk & 127) * TOK_PER_BLK;

    {
        const int tl = tid & 31;
        const int d0 = (tid >> 5) * 32;
        const float* xp = x + (size_t)b * DD * TT + t0 + tl;
        for (int dd = 0; dd < 32; ++dd) {
            int d = d0 + dd;
            r_lds[tl][d] = xp[(size_t)d * TT];
        }
    }
    __syncthreads();

    const int ty = tid >> 4;
    const int tx = tid & 15;

    for (int q = 0; q < NQ; ++q) {
        const float* eb = cb + (size_t)q * BINS * DD;
        const float* es = esq + q * BINS;
        float b1[2] = {-1e30f, -1e30f}, b2[2] = {-1e30f, -1e30f};
        int   i1[2] = {0x7fffffff, 0x7fffffff}, i2[2] = {0x7fffffff, 0x7fffffff};

        for (int c = 0; c < BINS / BIN_CHUNK; ++c) {
            float acc[2][8];
            #pragma unroll
            for (int i = 0; i < 2; ++i)
                #pragma unroll
                for (int j = 0; j < 8; ++j) acc[i][j] = 0.f;

            for (int kc = 0; kc < DD / KC; ++kc) {
                __syncthreads();
                {
                    const int col  = tid & 7;
                    const int row0 = tid >> 3;
                    const float* src = eb + (size_t)(c * BIN_CHUNK) * DD + kc * KC;
                    #pragma unroll
                    for (int rr = 0; rr < 4; ++rr) {
                        int row = row0 + rr * 32;
                        float4 v = *(const float4*)(src + (size_t)row * DD + col * 4);
                        *(float4*)&e_lds[row][col * 4] = v;
                    }
                }
                __syncthreads();
                #pragma unroll
                for (int k4 = 0; k4 < KC / 4; ++k4) {
                    float4 r0 = *(const float4*)&r_lds[tx][kc * KC + k4 * 4];
                    float4 r1 = *(const float4*)&r_lds[tx + 16][kc * KC + k4 * 4];
                    #pragma unroll
                    for (int bi = 0; bi < 8; ++bi) {
                        float4 e4 = *(const float4*)&e_lds[ty + 16 * bi][k4 * 4];
                        acc[0][bi] += r0.x * e4.x + r0.y * e4.y + r0.z * e4.z + r0.w * e4.w;
                        acc[1][bi] += r1.x * e4.x + r1.y * e4.y + r1.z * e4.z + r1.w * e4.w;
                    }
                }
            }
            #pragma unroll
            for (int bi = 0; bi < 8; ++bi) {
                int bin = c * BIN_CHUNK + ty + 16 * bi;
                float half_esq = 0.5f * es[bin];
                float s0 = acc[0][bi] - half_esq;
                float s1v = acc[1][bi] - half_esq;
                FUPD2(s0, bin, b1[0], i1[0], b2[0], i2[0]);
                FUPD2(s1v, bin, b1[1], i1[1], b2[1], i2[1]);
            }
        }

        #pragma unroll
        for (int k = 0; k < 2; ++k) {
            red_s[ty][k][tx]      = k ? b2[0] : b1[0];
            red_i[ty][k][tx]      = k ? i2[0] : i1[0];
            red_s[ty][k][tx + 16] = k ? b2[1] : b1[1];
            red_i[ty][k][tx + 16] = k ? i2[1] : i1[1];
        }
        __syncthreads();

        if (tid < TOK_PER_BLK) {
            float g1 = -1e30f, g2 = -1e30f; int gi1 = 0x7fffffff, gi2 = 0x7fffffff;
            #pragma unroll
            for (int j = 0; j < 16; ++j) {
                #pragma unroll
                for (int k = 0; k < 2; ++k) {
                    float s = red_s[j][k][tid]; int ii = red_i[j][k][tid];
                    FUPD2(s, ii, g1, gi1, g2, gi2);
                }
            }
            int bif;
            if (g1 - g2 <= DELTA) {
                const float* rrow = r_lds[tid];
                double sc[2]; int id2[2] = { gi1, gi2 };
                for (int cc = 0; cc < 2; ++cc) {
                    const float* ep = eb + (size_t)id2[cc] * DD;
                    double acc2 = 0.0;
                    #pragma unroll 4
                    for (int d = 0; d < DD; ++d) {
                        double ev = (double)ep[d];
                        acc2 += ev * (2.0 * (double)rrow[d] - ev);
                    }
                    sc[cc] = acc2;
                }
                bif = (sc[0] > sc[1] || (sc[0] == sc[1] && id2[0] < id2[1])) ? id2[0] : id2[1];
            } else {
                bif = gi1;
            }
            best_lds[tid] = bif;
            out[OUTQ + (size_t)q * (BB * TT) + (size_t)b * TT + t0 + tid] = (float)bif;
        }
        __syncthreads();

        {
            const int tok  = tid >> 3;
            const int part = tid & 7;
            const int bin  = best_lds[tok];
            const float* ep = eb + (size_t)bin * DD + part * 32;
            float* rp = &r_lds[tok][part * 32];
            #pragma unroll
            for (int dd = 0; dd < 32; ++dd) rp[dd] -= ep[dd];
        }
        __syncthreads();
    }

    {
        const int tl = tid & 31;
        const int d0 = (tid >> 5) * 32;
        const float* xp = x + (size_t)b * DD * TT + t0 + tl;
        float*       op = out + (size_t)b * DD * TT + t0 + tl;
        for (int dd = 0; dd < 32; ++dd) {
            int d = d0 + dd;
            op[(size_t)d * TT] = xp[(size_t)d * TT] - r_lds[tl][d];
        }
    }
}

extern "C" void kernel_launch(void* const* d_in, const int* in_sizes, int n_in,
                              void* d_out, int out_size, void* d_ws, size_t ws_size,
                              hipStream_t stream) {
    const float* x  = (const float*)d_in[0];
    const float* cb = (const float*)d_in[1];
    float* out = (float*)d_out;

    const size_t PK_BYTES = (size_t)NQ * BINS * DD * 4;       // 8 MB packed codebook
    const size_t NEED = PK_BYTES + (size_t)NQ * BINS * 4;     // + half-esq

    if (ws_size >= NEED) {
        unsigned* pk = (unsigned*)d_ws;
        float* hesq  = (float*)((char*)d_ws + PK_BYTES);
        rvq_pack<<<(NQ * BINS * DD / 4) / 256, 256, 0, stream>>>(cb, pk);
        rvq_esq_half<<<NQ, 256, 0, stream>>>(cb, hesq);
        rvq_mfma_kernel<<<256, 512, 0, stream>>>(x, cb, pk, hesq, out);
    } else {
        float* esq = (float*)d_ws;
        rvq_esq_kernel<<<NQ, 256, 0, stream>>>(cb, esq);
        rvq_main_kernel<<<(BB * TT) / TOK_PER_BLK, 256, 0, stream>>>(x, cb, esq, out);
    }
}

// Round 4
// 803.828 us; speedup vs baseline: 16.6809x; 1.0466x over previous
//
#include <hip/hip_runtime.h>

// Residual VQ forward: x [B=16, D=256, T=4096] fp32, codebooks [NQ=8, BINS=1024, D=256] fp32.
// d_out = quantized [B,D,T] fp32 ++ codes [NQ,B,T] as float.
// MFMA path: split-bf16 (hi/lo) 3-term GEMM, top-2 + fp64-exact refinement gate.
// Round 4: no spill (256 VGPR budget), pre-swizzled codebook + global_load_lds staging.

#define BB   16
#define DD   256
#define TT   4096
#define NQ   8
#define BINS 1024
#define DELTA 0.0078125f
#define OUTQ ((size_t)BB * DD * TT)

typedef __attribute__((ext_vector_type(8))) short bfrag;
typedef __attribute__((ext_vector_type(8))) unsigned short ushort8;
typedef __attribute__((ext_vector_type(4))) float facc;

__device__ inline float bfh2f(unsigned short h) {
    union { unsigned u; float f; } cv; cv.u = ((unsigned)h) << 16; return cv.f;
}
__device__ inline unsigned short f2bf(float f) {
    union { float f; unsigned u; } cv; cv.f = f;
    unsigned r = cv.u + 0x7fff + ((cv.u >> 16) & 1);
    return (unsigned short)(r >> 16);
}

#define MFMA(A, B, C) __builtin_amdgcn_mfma_f32_16x16x32_bf16((A), (B), (C), 0, 0, 0)

#define UPD2(S, BIN, S1, I1, S2, I2) { \
    bool _g1 = (S) > (S1); \
    bool _g2 = (S) > (S2); \
    S2 = _g1 ? (S1) : (_g2 ? (S) : (S2)); \
    I2 = _g1 ? (I1) : (_g2 ? (BIN) : (I2)); \
    S1 = _g1 ? (S) : (S1); \
    I1 = _g1 ? (BIN) : (I1); }

// ---------- pack kernel: fp32 codebook -> pre-swizzled hi/lo bf16 planes ----------
// Chunk cc = q*32 + ch covers bins ch*32..+31 of book q. Per chunk: 32 KB =
// [2 terms][16 planes][512 shorts]; plane p = nf*8 + s holds bins nf*16..+15,
// k-slice s; short pos = g*128 + c*8 + j  <->  (bin = base+nf*16+c, d = s*32+g*8+j).
// This is byte-for-byte the order rvq_mfma2_kernel's DMA+ds_read consumes.
__global__ __launch_bounds__(256)
void rvq_pack_swz(const float* __restrict__ cb, unsigned short* __restrict__ pks) {
    int gid = blockIdx.x * 256 + threadIdx.x;       // (q, bin, s)
    int s   = gid & 7;
    int bin = (gid >> 3) & 1023;
    int q   = gid >> 13;
    const float* src = cb + ((size_t)(q * BINS + bin)) * DD + s * 32;
    int cc    = q * 32 + (bin >> 5);
    int nf    = (bin >> 4) & 1;
    int c     = bin & 15;
    int plane = nf * 8 + s;
    size_t base = (size_t)cc * 16384 + (size_t)plane * 512 + c * 8;   // short units
    #pragma unroll
    for (int g = 0; g < 4; ++g) {
        float4 v0 = *(const float4*)(src + g * 8);
        float4 v1 = *(const float4*)(src + g * 8 + 4);
        float vv[8] = { v0.x, v0.y, v0.z, v0.w, v1.x, v1.y, v1.z, v1.w };
        ushort8 h8, l8;
        #pragma unroll
        for (int j = 0; j < 8; ++j) {
            unsigned short h = f2bf(vv[j]);
            h8[j] = h;
            l8[j] = f2bf(vv[j] - bfh2f(h));
        }
        *(ushort8*)&pks[base + g * 128]        = h8;   // term 0 (hi)
        *(ushort8*)&pks[base + 8192 + g * 128] = l8;   // term 1 (lo), +16*512 shorts
    }
}

__global__ __launch_bounds__(256)
void rvq_esq_half(const float* __restrict__ cb, float* __restrict__ hesq) {
    int q = blockIdx.x;
    const float* e = cb + (size_t)q * BINS * DD;
    for (int bin = threadIdx.x; bin < BINS; bin += 256) {
        const float4* row = (const float4*)(e + (size_t)bin * DD);
        float s = 0.f;
        #pragma unroll 8
        for (int i = 0; i < DD / 4; ++i) {
            float4 v = row[i];
            s += v.x * v.x + v.y * v.y + v.z * v.z + v.w * v.w;
        }
        hesq[q * BINS + bin] = 0.5f * s;
    }
}

// ---------- main MFMA kernel: 512 blocks x 256 thr (4 waves), 128 tokens/block ----------
__global__ __launch_bounds__(256, 2)
void rvq_mfma2_kernel(const float* __restrict__ x, const float* __restrict__ cb,
                      const unsigned short* __restrict__ pks, const float* __restrict__ hesq,
                      float* __restrict__ out)
{
    __shared__ alignas(16) short btile[2][2][16][512];   // 64 KB, double-buffered chunk
    __shared__ unsigned short best_lds[4][32];
    __shared__ unsigned short hist_lds[4][NQ][32];

    const int tid = threadIdx.x;
    const int w   = tid >> 6;
    const int l   = tid & 63;
    const int c   = l & 15;
    const int g   = l >> 4;

    const int blk = blockIdx.x;        // 512 blocks
    const int b   = blk >> 5;          // 32 blocks per batch element
    const int t0  = (blk & 31) * 128;
    const int tw  = t0 + w * 32;

    // per-lane DMA source base: wave w stages bytes [w*8K, w*8K+8K) of each 32 KB chunk
    const char* gsrc0 = (const char*)pks + w * 8192 + (l << 4);

    auto issue_chunk = [&](int cc, int bu) {
        cc &= 255;
        const char* src = gsrc0 + (size_t)cc * 32768;
        char* dst = (char*)(&btile[bu][0][0][0]) + w * 8192;
        #pragma unroll
        for (int i = 0; i < 8; ++i) {
            __builtin_amdgcn_global_load_lds(
                (const __attribute__((address_space(1))) unsigned int*)(src + i * 1024),
                (__attribute__((address_space(3))) unsigned int*)(dst + i * 1024),
                16, 0, 0);
        }
    };

    issue_chunk(0, 0);   // prefetch chunk 0 under the A-init loads

    // ---- A init: residual = x, split to hi/lo MFMA fragments ----
    bfrag ah[2][8], al[2][8];
    {
        const float* xb = x + (size_t)b * DD * TT;
        #pragma unroll
        for (int m = 0; m < 2; ++m) {
            int t = tw + m * 16 + c;
            #pragma unroll
            for (int s = 0; s < 8; ++s) {
                #pragma unroll
                for (int j = 0; j < 8; ++j) {
                    int d = s * 32 + g * 8 + j;
                    float v = xb[(size_t)d * TT + t];
                    unsigned short h = f2bf(v);
                    float rem = v - bfh2f(h);
                    ah[m][s][j] = (short)h;
                    al[m][s][j] = (short)f2bf(rem);
                }
            }
        }
    }
    __syncthreads();   // drains vmcnt -> chunk 0 resident

    // per-slot top-2 state: slot (m, j) = token m*16 + 4*g + j
    float s1[2][4], s2[2][4];
    int   i1[2][4], i2[2][4];

    auto reset_slots = [&]() {
        #pragma unroll
        for (int m = 0; m < 2; ++m)
            #pragma unroll
            for (int j = 0; j < 4; ++j) {
                s1[m][j] = -1e30f; s2[m][j] = -1e30f;
                i1[m][j] = 0x7fffffff; i2[m][j] = 0x7fffffff;
            }
    };

    auto compute_chunk = [&](int bu, int qq, int ch) {
        facc a00 = {0.f,0.f,0.f,0.f}, a01 = {0.f,0.f,0.f,0.f};
        facc a10 = {0.f,0.f,0.f,0.f}, a11 = {0.f,0.f,0.f,0.f};
        const int roff = g * 128 + c * 8;
        const float* hq = hesq + qq * BINS + ch * 32;
        float q0 = hq[c], q1 = hq[16 + c];
        __builtin_amdgcn_s_setprio(1);
        #pragma unroll
        for (int s = 0; s < 8; ++s) {
            bfrag bh0 = *(const bfrag*)&btile[bu][0][s][roff];
            bfrag bh1 = *(const bfrag*)&btile[bu][0][8 + s][roff];
            bfrag bl0 = *(const bfrag*)&btile[bu][1][s][roff];
            bfrag bl1 = *(const bfrag*)&btile[bu][1][8 + s][roff];
            a00 = MFMA(ah[0][s], bh0, a00);
            a10 = MFMA(ah[1][s], bh0, a10);
            a01 = MFMA(ah[0][s], bh1, a01);
            a11 = MFMA(ah[1][s], bh1, a11);
            a00 = MFMA(al[0][s], bh0, a00);
            a10 = MFMA(al[1][s], bh0, a10);
            a01 = MFMA(al[0][s], bh1, a01);
            a11 = MFMA(al[1][s], bh1, a11);
            a00 = MFMA(ah[0][s], bl0, a00);
            a10 = MFMA(ah[1][s], bl0, a10);
            a01 = MFMA(ah[0][s], bl1, a01);
            a11 = MFMA(ah[1][s], bl1, a11);
        }
        __builtin_amdgcn_s_setprio(0);
        int bin0 = ch * 32 + c;
        #pragma unroll
        for (int j = 0; j < 4; ++j) {
            float v;
            v = a00[j] - q0; UPD2(v, bin0,      s1[0][j], i1[0][j], s2[0][j], i2[0][j]);
            v = a01[j] - q1; UPD2(v, bin0 + 16, s1[0][j], i1[0][j], s2[0][j], i2[0][j]);
            v = a10[j] - q0; UPD2(v, bin0,      s1[1][j], i1[1][j], s2[1][j], i2[1][j]);
            v = a11[j] - q1; UPD2(v, bin0 + 16, s1[1][j], i1[1][j], s2[1][j], i2[1][j]);
        }
    };

    auto stage_end = [&](int qq) {
        // cross-lane top-2 merge over the 16 column lanes
        #pragma unroll
        for (int m = 0; m < 2; ++m)
            #pragma unroll
            for (int j = 0; j < 4; ++j) {
                float a1 = s1[m][j], a2 = s2[m][j];
                int   x1 = i1[m][j], x2 = i2[m][j];
                #pragma unroll
                for (int mk = 1; mk < 16; mk <<= 1) {
                    float b1 = __shfl_xor(a1, mk), b2 = __shfl_xor(a2, mk);
                    int   y1 = __shfl_xor(x1, mk), y2 = __shfl_xor(x2, mk);
                    bool bG = (b1 > a1) || (b1 == a1 && y1 < x1);
                    float w1 = bG ? b1 : a1; int wi1 = bG ? y1 : x1;
                    float ls = bG ? a1 : b1; int li  = bG ? x1 : y1;
                    float o2 = bG ? b2 : a2; int oi  = bG ? y2 : x2;
                    bool sG = (ls > o2) || (ls == o2 && li < oi);
                    a1 = w1; x1 = wi1;
                    a2 = sG ? ls : o2; x2 = sG ? li : oi;
                }
                s1[m][j] = a1; i1[m][j] = x1; s2[m][j] = a2; i2[m][j] = x2;
            }

        int bch[2][4];
        bool need = false;
        #pragma unroll
        for (int m = 0; m < 2; ++m)
            #pragma unroll
            for (int j = 0; j < 4; ++j) {
                bch[m][j] = i1[m][j];
                need = need || (s1[m][j] - s2[m][j] <= DELTA);
            }

        if (__any(need)) {
            // rare: exact fp32 residual chain + fp64 re-score of the two candidates
            #pragma unroll
            for (int m = 0; m < 2; ++m)
                #pragma unroll
                for (int j = 0; j < 4; ++j) {
                    unsigned long long nm = __ballot(s1[m][j] - s2[m][j] <= DELTA);
                    if (nm) {
                        for (int g2 = 0; g2 < 4; ++g2) {
                            if ((nm >> (g2 * 16)) & 1ull) {
                                int c1 = __shfl(i1[m][j], g2 * 16);
                                int c2 = __shfl(i2[m][j], g2 * 16);
                                int tkl = m * 16 + g2 * 4 + j;
                                int t = tw + tkl;
                                double p1 = 0.0, p2 = 0.0;
                                const float* e1p = cb + (size_t)(qq * BINS + c1) * DD;
                                const float* e2p = cb + (size_t)(qq * BINS + c2) * DD;
                                #pragma unroll
                                for (int dd = 0; dd < 4; ++dd) {
                                    int d = l * 4 + dd;
                                    float rv = x[((size_t)b * DD + d) * TT + t];
                                    for (int k = 0; k < qq; ++k) {
                                        int hb = hist_lds[w][k][tkl];
                                        rv -= cb[(size_t)(k * BINS + hb) * DD + d];
                                    }
                                    float e1v = e1p[d], e2v = e2p[d];
                                    p1 += (double)e1v * (2.0 * (double)rv - (double)e1v);
                                    p2 += (double)e2v * (2.0 * (double)rv - (double)e2v);
                                }
                                #pragma unroll
                                for (int mk = 1; mk < 64; mk <<= 1) {
                                    p1 += __shfl_xor(p1, mk);
                                    p2 += __shfl_xor(p2, mk);
                                }
                                int wb = (p1 > p2 || (p1 == p2 && c1 < c2)) ? c1 : c2;
                                if (g == g2) bch[m][j] = wb;
                            }
                        }
                    }
                }
        }

        // writes: codes + per-wave best/history
        if (c == 0) {
            #pragma unroll
            for (int m = 0; m < 2; ++m)
                #pragma unroll
                for (int j = 0; j < 4; ++j) {
                    int tkl = m * 16 + g * 4 + j;
                    best_lds[w][tkl] = (unsigned short)bch[m][j];
                    hist_lds[w][qq][tkl] = (unsigned short)bch[m][j];
                    out[OUTQ + ((size_t)qq * BB + b) * TT + tw + tkl] = (float)bch[m][j];
                }
        }

        // residual update from EXACT fp32 codebook row: r -= e[best], re-split hi/lo
        #pragma unroll
        for (int m = 0; m < 2; ++m) {
            int bin = best_lds[w][m * 16 + c];
            const float* ep = cb + (size_t)(qq * BINS + bin) * DD + g * 8;
            #pragma unroll
            for (int s = 0; s < 8; ++s) {
                float4 e0 = *(const float4*)(ep + s * 32);
                float4 e1 = *(const float4*)(ep + s * 32 + 4);
                float ev[8] = { e0.x, e0.y, e0.z, e0.w, e1.x, e1.y, e1.z, e1.w };
                #pragma unroll
                for (int j = 0; j < 8; ++j) {
                    float rv = bfh2f((unsigned short)ah[m][s][j]) + bfh2f((unsigned short)al[m][s][j]);
                    float nr = rv - ev[j];
                    unsigned short nh = f2bf(nr);
                    float rem = nr - bfh2f(nh);
                    ah[m][s][j] = (short)nh;
                    al[m][s][j] = (short)f2bf(rem);
                }
            }
        }
    };

    // ---- main loop: 8 stages x 32 chunks, T3 2-phase (issue-next / compute / barrier) ----
    int buf = 0;
    for (int q = 0; q < NQ; ++q) {
        reset_slots();
        for (int ch = 0; ch < 32; ++ch) {
            issue_chunk(q * 32 + ch + 1, buf ^ 1);
            compute_chunk(buf, q, ch);
            if (ch == 31) stage_end(q);
            __syncthreads();           // drains vmcnt(0): next chunk's DMA resident
            buf ^= 1;
        }
    }

    // ---- final: quantized = x - residual ----
    {
        const float* xb = x + (size_t)b * DD * TT;
        float* ob = out + (size_t)b * DD * TT;
        #pragma unroll
        for (int m = 0; m < 2; ++m) {
            int t = tw + m * 16 + c;
            #pragma unroll
            for (int s = 0; s < 8; ++s)
                #pragma unroll
                for (int j = 0; j < 8; ++j) {
                    int d = s * 32 + g * 8 + j;
                    float rv = bfh2f((unsigned short)ah[m][s][j]) + bfh2f((unsigned short)al[m][s][j]);
                    ob[(size_t)d * TT + t] = xb[(size_t)d * TT + t] - rv;
                }
        }
    }
}

// ================= fallback fp32 path (round-2, known-good) =================
#define TOK_PER_BLK 32
#define BIN_CHUNK   128
#define KC          32
#define EPAD        36
#define RPAD        260

#define FUPD2(S, BIN, B1, I1, B2, I2)                                        \
    if ((S) > (B2) || ((S) == (B2) && (BIN) < (I2))) {                      \
        if ((S) > (B1) || ((S) == (B1) && (BIN) < (I1))) {                  \
            B2 = B1; I2 = I1; B1 = (S); I1 = (BIN);                         \
        } else { B2 = (S); I2 = (BIN); }                                    \
    }

__global__ __launch_bounds__(256, 2)
void rvq_esq_kernel(const float* __restrict__ cb, float* __restrict__ esq) {
    int q = blockIdx.x;
    const float* e = cb + (size_t)q * BINS * DD;
    for (int bin = threadIdx.x; bin < BINS; bin += 256) {
        const float4* row = (const float4*)(e + (size_t)bin * DD);
        float s = 0.f;
        #pragma unroll 8
        for (int i = 0; i < DD / 4; ++i) {
            float4 v = row[i];
            s += v.x * v.x + v.y * v.y + v.z * v.z + v.w * v.w;
        }
        esq[q * BINS + bin] = s;
    }
}

__global__ __launch_bounds__(256, 2)
void rvq_main_kernel(const float* __restrict__ x, const float* __restrict__ cb,
                     const float* __restrict__ esq, float* __restrict__ out) {
    __shared__ float r_lds[TOK_PER_BLK][RPAD];
    __shared__ float e_lds[BIN_CHUNK][EPAD];
    __shared__ float red_s[16][2][TOK_PER_BLK];
    __shared__ int   red_i[16][2][TOK_PER_BLK];
    __shared__ int   best_lds2[TOK_PER_BLK];

    const int tid = threadIdx.x;
    const int blk = blockIdx.x;
    const int b   = blk >> 7;
    const int t0  = (blk & 127) * TOK_PER_BLK;

    {
        const int tl = tid & 31;
        const int d0 = (tid >> 5) * 32;
        const float* xp = x + (size_t)b * DD * TT + t0 + tl;
        for (int dd = 0; dd < 32; ++dd) {
            int d = d0 + dd;
            r_lds[tl][d] = xp[(size_t)d * TT];
        }
    }
    __syncthreads();

    const int ty = tid >> 4;
    const int tx = tid & 15;

    for (int q = 0; q < NQ; ++q) {
        const float* eb = cb + (size_t)q * BINS * DD;
        const float* es = esq + q * BINS;
        float b1[2] = {-1e30f, -1e30f}, b2[2] = {-1e30f, -1e30f};
        int   i1[2] = {0x7fffffff, 0x7fffffff}, i2[2] = {0x7fffffff, 0x7fffffff};

        for (int cch = 0; cch < BINS / BIN_CHUNK; ++cch) {
            float acc[2][8];
            #pragma unroll
            for (int i = 0; i < 2; ++i)
                #pragma unroll
                for (int j = 0; j < 8; ++j) acc[i][j] = 0.f;

            for (int kc = 0; kc < DD / KC; ++kc) {
                __syncthreads();
                {
                    const int col  = tid & 7;
                    const int row0 = tid >> 3;
                    const float* src = eb + (size_t)(cch * BIN_CHUNK) * DD + kc * KC;
                    #pragma unroll
                    for (int rr = 0; rr < 4; ++rr) {
                        int row = row0 + rr * 32;
                        float4 v = *(const float4*)(src + (size_t)row * DD + col * 4);
                        *(float4*)&e_lds[row][col * 4] = v;
                    }
                }
                __syncthreads();
                #pragma unroll
                for (int k4 = 0; k4 < KC / 4; ++k4) {
                    float4 r0 = *(const float4*)&r_lds[tx][kc * KC + k4 * 4];
                    float4 r1 = *(const float4*)&r_lds[tx + 16][kc * KC + k4 * 4];
                    #pragma unroll
                    for (int bi = 0; bi < 8; ++bi) {
                        float4 e4 = *(const float4*)&e_lds[ty + 16 * bi][k4 * 4];
                        acc[0][bi] += r0.x * e4.x + r0.y * e4.y + r0.z * e4.z + r0.w * e4.w;
                        acc[1][bi] += r1.x * e4.x + r1.y * e4.y + r1.z * e4.z + r1.w * e4.w;
                    }
                }
            }
            #pragma unroll
            for (int bi = 0; bi < 8; ++bi) {
                int bin = cch * BIN_CHUNK + ty + 16 * bi;
                float half_esq = 0.5f * es[bin];
                float s0 = acc[0][bi] - half_esq;
                float s1v = acc[1][bi] - half_esq;
                FUPD2(s0, bin, b1[0], i1[0], b2[0], i2[0]);
                FUPD2(s1v, bin, b1[1], i1[1], b2[1], i2[1]);
            }
        }

        #pragma unroll
        for (int k = 0; k < 2; ++k) {
            red_s[ty][k][tx]      = k ? b2[0] : b1[0];
            red_i[ty][k][tx]      = k ? i2[0] : i1[0];
            red_s[ty][k][tx + 16] = k ? b2[1] : b1[1];
            red_i[ty][k][tx + 16] = k ? i2[1] : i1[1];
        }
        __syncthreads();

        if (tid < TOK_PER_BLK) {
            float g1 = -1e30f, g2 = -1e30f; int gi1 = 0x7fffffff, gi2 = 0x7fffffff;
            #pragma unroll
            for (int j = 0; j < 16; ++j) {
                #pragma unroll
                for (int k = 0; k < 2; ++k) {
                    float s = red_s[j][k][tid]; int ii = red_i[j][k][tid];
                    FUPD2(s, ii, g1, gi1, g2, gi2);
                }
            }
            int bif;
            if (g1 - g2 <= DELTA) {
                const float* rrow = r_lds[tid];
                double sc[2]; int id2[2] = { gi1, gi2 };
                for (int cc2 = 0; cc2 < 2; ++cc2) {
                    const float* ep = eb + (size_t)id2[cc2] * DD;
                    double acc2 = 0.0;
                    #pragma unroll 4
                    for (int d = 0; d < DD; ++d) {
                        double ev = (double)ep[d];
                        acc2 += ev * (2.0 * (double)rrow[d] - ev);
                    }
                    sc[cc2] = acc2;
                }
                bif = (sc[0] > sc[1] || (sc[0] == sc[1] && id2[0] < id2[1])) ? id2[0] : id2[1];
            } else {
                bif = gi1;
            }
            best_lds2[tid] = bif;
            out[OUTQ + (size_t)q * (BB * TT) + (size_t)b * TT + t0 + tid] = (float)bif;
        }
        __syncthreads();

        {
            const int tok  = tid >> 3;
            const int part = tid & 7;
            const int bin  = best_lds2[tok];
            const float* ep = eb + (size_t)bin * DD + part * 32;
            float* rp = &r_lds[tok][part * 32];
            #pragma unroll
            for (int dd = 0; dd < 32; ++dd) rp[dd] -= ep[dd];
        }
        __syncthreads();
    }

    {
        const int tl = tid & 31;
        const int d0 = (tid >> 5) * 32;
        const float* xp = x + (size_t)b * DD * TT + t0 + tl;
        float*       op = out + (size_t)b * DD * TT + t0 + tl;
        for (int dd = 0; dd < 32; ++dd) {
            int d = d0 + dd;
            op[(size_t)d * TT] = xp[(size_t)d * TT] - r_lds[tl][d];
        }
    }
}

extern "C" void kernel_launch(void* const* d_in, const int* in_sizes, int n_in,
                              void* d_out, int out_size, void* d_ws, size_t ws_size,
                              hipStream_t stream) {
    const float* x  = (const float*)d_in[0];
    const float* cb = (const float*)d_in[1];
    float* out = (float*)d_out;

    const size_t PKS_BYTES = (size_t)NQ * BINS * DD * 2 * 2;   // 8 MB pre-swizzled hi/lo
    const size_t NEED = PKS_BYTES + (size_t)NQ * BINS * 4;     // + half-esq

    if (ws_size >= NEED) {
        unsigned short* pks = (unsigned short*)d_ws;
        float* hesq = (float*)((char*)d_ws + PKS_BYTES);
        rvq_pack_swz<<<(NQ * BINS * 8) / 256, 256, 0, stream>>>(cb, pks);
        rvq_esq_half<<<NQ, 256, 0, stream>>>(cb, hesq);
        rvq_mfma2_kernel<<<512, 256, 0, stream>>>(x, cb, pks, hesq, out);
    } else {
        float* esq = (float*)d_ws;
        rvq_esq_kernel<<<NQ, 256, 0, stream>>>(cb, esq);
        rvq_main_kernel<<<(BB * TT) / TOK_PER_BLK, 256, 0, stream>>>(x, cb, esq, out);
    }
}